// Round 4
// baseline (244.921 us; speedup 1.0000x reference)
//
#include <hip/hip_runtime.h>
#include <hip/hip_bf16.h>

typedef unsigned short ushort_t;
typedef __attribute__((ext_vector_type(8))) short short8;
typedef __attribute__((ext_vector_type(4))) float floatx4;

#define G_  129
#define F_  96
#define O_  96
#define T_  512
#define KD  288   // K*F, kd = kk*96 + f
#define LDA 40    // Xl padded row stride (32 + 8)
#define LDB 296   // Wl padded row stride (288 + 8)

// f32 -> bf16 (round-to-nearest-even; inputs are finite so no NaN handling)
__device__ __forceinline__ ushort_t f2bf(float f) {
    unsigned u = __builtin_bit_cast(unsigned, f);
    u += 0x7FFFu + ((u >> 16) & 1u);
    return (ushort_t)(u >> 16);
}

// Permute+convert weight: w (f32, [G,O,F,K], f*3+kk contig) -> wt (bf16, [G,O,kd]),
// kd = kk*96+f. Indexed by OUTPUT position so the 2B writes are fully coalesced;
// the scattered 4B reads stay within a 1152B window per (g,o) row -> L1/L2 absorbs.
__global__ void wt_permute(const float* __restrict__ w, ushort_t* __restrict__ wt) {
    int i = blockIdx.x * 256 + threadIdx.x;
    const int total = G_ * O_ * KD;
    if (i >= total) return;
    int base = i / KD;          // g*O + o
    int kd = i - base * KD;     // kk*96 + f
    int kk = kd / F_;
    int f  = kd - kk * F_;
    wt[i] = f2bf(w[base * KD + f * 3 + kk]);
}

__global__ __launch_bounds__(256, 2) void conv_mfma(
    const float* __restrict__ x, const ushort_t* __restrict__ wt,
    const float* __restrict__ bias, float* __restrict__ out)
{
    __shared__ __align__(16) ushort_t Wl[O_ * LDB];      // 56,832 B
    __shared__ __align__(16) ushort_t Xl[2][128 * LDA];  // 20,480 B

    const int g   = blockIdx.y;
    const int m0  = blockIdx.x * 128;
    const int tid = threadIdx.x;
    const int wave = tid >> 6;
    const int lane = tid & 63;
    const int ln = lane & 15;
    const int q  = lane >> 4;

    // Stage this group's full weight into LDS: 96 rows x 288 bf16 (padded stride 296)
    {
        const ushort_t* src = wt + (size_t)g * (O_ * KD);
        for (int idx = tid; idx < O_ * 36; idx += 256) {
            int o = idx / 36;
            int s = idx - o * 36;
            *(short8*)&Wl[o * LDB + s * 8] = *(const short8*)&src[o * KD + s * 8];
        }
    }

    // Stage A chunk c (32 k-values = one f-block of one kernel tap) into Xl[c&1],
    // converting f32 -> bf16 inline. 512 tasks: 128 rows x 4 segments of 8 elems.
    auto stageA = [&](int c) {
        int kk = c / 3;
        int fb = (c - kk * 3) * 32;
        int buf = c & 1;
        #pragma unroll
        for (int i = 0; i < 2; ++i) {
            int idx = tid + i * 256;
            int r = idx >> 2;
            int seg = idx & 3;
            int m = m0 + r;
            int b = m >> 9;
            int t = m & 511;
            int tt = t + kk - 1;
            short8 v = {0,0,0,0,0,0,0,0};
            if ((unsigned)tt < (unsigned)T_) {
                const float* p = x + ((size_t)((b * T_ + tt) * G_ + g) * F_ + fb + seg * 8);
                floatx4 f0 = *(const floatx4*)p;
                floatx4 f1 = *(const floatx4*)(p + 4);
                v[0] = (short)f2bf(f0[0]); v[1] = (short)f2bf(f0[1]);
                v[2] = (short)f2bf(f0[2]); v[3] = (short)f2bf(f0[3]);
                v[4] = (short)f2bf(f1[0]); v[5] = (short)f2bf(f1[1]);
                v[6] = (short)f2bf(f1[2]); v[7] = (short)f2bf(f1[3]);
            }
            *(short8*)&Xl[buf][r * LDA + seg * 8] = v;
        }
    };

    floatx4 acc[2][6];
    #pragma unroll
    for (int s = 0; s < 2; ++s)
        #pragma unroll
        for (int nt = 0; nt < 6; ++nt)
            acc[s][nt] = (floatx4){0.f, 0.f, 0.f, 0.f};

    stageA(0);
    __syncthreads();

    for (int c = 0; c < 9; ++c) {
        if (c < 8) stageA(c + 1);   // prefetch next chunk into the other buffer
        int buf = c & 1;
        const short8 a0 = *(const short8*)&Xl[buf][(wave * 32 + ln) * LDA + q * 8];
        const short8 a1 = *(const short8*)&Xl[buf][(wave * 32 + 16 + ln) * LDA + q * 8];
        #pragma unroll
        for (int nt = 0; nt < 6; ++nt) {
            const short8 bb = *(const short8*)&Wl[(nt * 16 + ln) * LDB + c * 32 + q * 8];
            acc[0][nt] = __builtin_amdgcn_mfma_f32_16x16x32_bf16(a0, bb, acc[0][nt], 0, 0, 0);
            acc[1][nt] = __builtin_amdgcn_mfma_f32_16x16x32_bf16(a1, bb, acc[1][nt], 0, 0, 0);
        }
        __syncthreads();
    }

    // Epilogue: D row = q*4 + reg, col = ln (m89/m91-verified layout), + bias.
    // Output is FLOAT32 (reference's dtype). 16 lanes (ln) cover 16 consecutive
    // o -> 64B contiguous segments per store slice.
    #pragma unroll
    for (int s = 0; s < 2; ++s) {
        int mbase = m0 + wave * 32 + s * 16 + q * 4;
        #pragma unroll
        for (int nt = 0; nt < 6; ++nt) {
            int o = nt * 16 + ln;
            float bv = bias[g * O_ + o];
            #pragma unroll
            for (int r = 0; r < 4; ++r) {
                int m = mbase + r;
                out[(size_t)(m * G_ + g) * O_ + o] = acc[s][nt][r] + bv;
            }
        }
    }
}

extern "C" void kernel_launch(void* const* d_in, const int* in_sizes, int n_in,
                              void* d_out, int out_size, void* d_ws, size_t ws_size,
                              hipStream_t stream) {
    const float* x    = (const float*)d_in[0];
    const float* w    = (const float*)d_in[1];
    const float* bias = (const float*)d_in[2];
    float* out = (float*)d_out;
    ushort_t* wt = (ushort_t*)d_ws;   // 129*96*288*2 = 7,133,184 B

    const int total_w = G_ * O_ * KD;
    wt_permute<<<dim3((total_w + 255) / 256), dim3(256), 0, stream>>>(w, wt);

    dim3 grid(2048 / 128, G_);
    conv_mfma<<<grid, dim3(256), 0, stream>>>(x, wt, bias, out);
}

// Round 5
// 239.154 us; speedup vs baseline: 1.0241x; 1.0241x over previous
//
#include <hip/hip_runtime.h>
#include <hip/hip_bf16.h>

typedef unsigned short ushort_t;
typedef __attribute__((ext_vector_type(8))) short short8;
typedef __attribute__((ext_vector_type(4))) float floatx4;

#define G_  129
#define F_  96
#define O_  96
#define T_  512
#define KD  288   // K*F, kd = kk*96 + f
#define LDB 296   // Wl padded row stride (288 + 8)

// f32 -> bf16 (round-to-nearest-even; inputs finite)
__device__ __forceinline__ ushort_t f2bf(float f) {
    unsigned u = __builtin_bit_cast(unsigned, f);
    u += 0x7FFFu + ((u >> 16) & 1u);
    return (ushort_t)(u >> 16);
}

// Permute+convert weight: w (f32, [G,O,F,K], f*3+kk contig) -> wt (bf16, [G,O,kd]),
// kd = kk*96+f. Output-indexed so 2B writes are coalesced; scattered 4B reads sit
// in a 1152B window per (g,o) row -> L1/L2 absorbs.
__global__ void wt_permute(const float* __restrict__ w, ushort_t* __restrict__ wt) {
    int i = blockIdx.x * 256 + threadIdx.x;
    const int total = G_ * O_ * KD;
    if (i >= total) return;
    int base = i / KD;          // g*O + o
    int kd = i - base * KD;     // kk*96 + f
    int kk = kd / F_;
    int f  = kd - kk * F_;
    wt[i] = f2bf(w[base * KD + f * 3 + kk]);
}

// 512 threads = 8 waves, M-tile 256, full O=96. LDS holds ONLY the group's
// weights (57KB -> 2 blocks/CU = 16 waves/CU). A goes global->register directly
// (8 contiguous f32 per fragment row-segment); NO barrier in the K-loop.
__global__ __launch_bounds__(512, 4) void conv_mfma(
    const float* __restrict__ x, const ushort_t* __restrict__ wt,
    const float* __restrict__ bias, float* __restrict__ out)
{
    __shared__ __align__(16) ushort_t Wl[O_ * LDB];   // 56,832 B

    const int g    = blockIdx.y;
    const int m0   = blockIdx.x * 256;
    const int tid  = threadIdx.x;
    const int wave = tid >> 6;
    const int lane = tid & 63;
    const int ln   = lane & 15;
    const int q    = lane >> 4;

    // Stage this group's weights: 96 rows x 288 bf16 (padded stride 296)
    {
        const ushort_t* src = wt + (size_t)g * (O_ * KD);
        for (int idx = tid; idx < O_ * 36; idx += 512) {
            int o = idx / 36;
            int s = idx - o * 36;
            *(short8*)&Wl[o * LDB + s * 8] = *(const short8*)&src[o * KD + s * 8];
        }
    }
    __syncthreads();   // the ONLY barrier

    // A-fragment rows owned by this lane (m89/m91 layout: A[m=ln][k=q*8+j])
    const int r0 = m0 + wave * 32 + ln;
    const int r1 = r0 + 16;
    const int b0 = r0 >> 9, t0 = r0 & 511;
    const int b1 = r1 >> 9, t1 = r1 & 511;

    floatx4 acc[2][6];
    #pragma unroll
    for (int s = 0; s < 2; ++s)
        #pragma unroll
        for (int nt = 0; nt < 6; ++nt)
            acc[s][nt] = (floatx4){0.f, 0.f, 0.f, 0.f};

    // Issue chunk-c A loads: chunk c = tap kk=c/3, f-block fb=(c%3)*32.
    // Lane reads f = fb + q*8 .. +8 (32B contiguous -> 2x dwordx4) per row.
    // OOB tap rows: clamp address (no fault), mask fragment to zero.
    auto issue = [&](int c, floatx4* f, bool* vld) {
        int kk = c / 3;
        int fb = (c - kk * 3) * 32;
        int tt0 = t0 + kk - 1, tt1 = t1 + kk - 1;
        vld[0] = (unsigned)tt0 < (unsigned)T_;
        vld[1] = (unsigned)tt1 < (unsigned)T_;
        int tc0 = tt0 < 0 ? 0 : (tt0 > T_ - 1 ? T_ - 1 : tt0);
        int tc1 = tt1 < 0 ? 0 : (tt1 > T_ - 1 ? T_ - 1 : tt1);
        const float* p0 = x + ((size_t)((b0 * T_ + tc0) * G_ + g) * F_ + fb + q * 8);
        const float* p1 = x + ((size_t)((b1 * T_ + tc1) * G_ + g) * F_ + fb + q * 8);
        f[0] = *(const floatx4*)p0;
        f[1] = *(const floatx4*)(p0 + 4);
        f[2] = *(const floatx4*)p1;
        f[3] = *(const floatx4*)(p1 + 4);
    };

    floatx4 pf[4];
    bool pv[2];
    issue(0, pf, pv);

    #pragma unroll
    for (int c = 0; c < 9; ++c) {
        floatx4 cur0 = pf[0], cur1 = pf[1], cur2 = pf[2], cur3 = pf[3];
        bool cv0 = pv[0], cv1 = pv[1];
        if (c < 8) issue(c + 1, pf, pv);   // depth-1 register prefetch

        short8 a0, a1;
        a0[0] = (short)f2bf(cur0[0]); a0[1] = (short)f2bf(cur0[1]);
        a0[2] = (short)f2bf(cur0[2]); a0[3] = (short)f2bf(cur0[3]);
        a0[4] = (short)f2bf(cur1[0]); a0[5] = (short)f2bf(cur1[1]);
        a0[6] = (short)f2bf(cur1[2]); a0[7] = (short)f2bf(cur1[3]);
        a1[0] = (short)f2bf(cur2[0]); a1[1] = (short)f2bf(cur2[1]);
        a1[2] = (short)f2bf(cur2[2]); a1[3] = (short)f2bf(cur2[3]);
        a1[4] = (short)f2bf(cur3[0]); a1[5] = (short)f2bf(cur3[1]);
        a1[6] = (short)f2bf(cur3[2]); a1[7] = (short)f2bf(cur3[3]);
        const short8 z = {0, 0, 0, 0, 0, 0, 0, 0};
        if (!cv0) a0 = z;
        if (!cv1) a1 = z;

        #pragma unroll
        for (int nt = 0; nt < 6; ++nt) {
            const short8 bb = *(const short8*)&Wl[(nt * 16 + ln) * LDB + c * 32 + q * 8];
            acc[0][nt] = __builtin_amdgcn_mfma_f32_16x16x32_bf16(a0, bb, acc[0][nt], 0, 0, 0);
            acc[1][nt] = __builtin_amdgcn_mfma_f32_16x16x32_bf16(a1, bb, acc[1][nt], 0, 0, 0);
        }
    }

    // Epilogue: D row = q*4 + reg, col = ln; + bias; f32 out (reference dtype).
    #pragma unroll
    for (int s = 0; s < 2; ++s) {
        int mbase = m0 + wave * 32 + s * 16 + q * 4;
        #pragma unroll
        for (int nt = 0; nt < 6; ++nt) {
            int o = nt * 16 + ln;
            float bv = bias[g * O_ + o];
            #pragma unroll
            for (int r = 0; r < 4; ++r) {
                int m = mbase + r;
                out[(size_t)(m * G_ + g) * O_ + o] = acc[s][nt][r] + bv;
            }
        }
    }
}

extern "C" void kernel_launch(void* const* d_in, const int* in_sizes, int n_in,
                              void* d_out, int out_size, void* d_ws, size_t ws_size,
                              hipStream_t stream) {
    const float* x    = (const float*)d_in[0];
    const float* w    = (const float*)d_in[1];
    const float* bias = (const float*)d_in[2];
    float* out = (float*)d_out;
    ushort_t* wt = (ushort_t*)d_ws;   // 129*96*288*2 = 7,133,184 B

    const int total_w = G_ * O_ * KD;
    wt_permute<<<dim3((total_w + 255) / 256), dim3(256), 0, stream>>>(w, wt);

    dim3 grid(2048 / 256, G_);
    conv_mfma<<<grid, dim3(512), 0, stream>>>(x, wt, bias, out);
}

// Round 7
// 218.524 us; speedup vs baseline: 1.1208x; 1.0944x over previous
//
#include <hip/hip_runtime.h>
#include <hip/hip_bf16.h>

typedef unsigned short ushort_t;
typedef __attribute__((ext_vector_type(8))) short short8;
typedef __attribute__((ext_vector_type(4))) float floatx4;

#define G_   129
#define F_   96
#define O_   96
#define T_   512
#define KD   288    // K*F, kd = kk*96 + f
#define LDB  296    // Wl padded row stride (288 + 8)
#define SROW 40     // x-slab row stride in ushorts (80 B) -> bank-conflict-free
#define SLAB (36 * SROW)   // per-wave slab: 36 rows (34 used) = 2880 B

// f32 -> bf16 RNE (finite inputs)
__device__ __forceinline__ unsigned f2bf(float f) {
    unsigned u = __builtin_bit_cast(unsigned, f);
    u += 0x7FFFu + ((u >> 16) & 1u);
    return u >> 16;
}
// packed pair f32x2 -> bf16x2 in one dword (integer pack; no class types)
__device__ __forceinline__ unsigned pk2(float a, float b) {
    return f2bf(a) | (f2bf(b) << 16);
}

// Permute+convert weight: w (f32, [G,O,F,K], f*3+kk contig) -> wt (bf16, [G,O,kd]),
// kd = kk*96+f. Output-indexed: 2B writes coalesced; scattered 4B reads live in a
// 1152B window per (g,o) row -> L1/L2 absorbs.
__global__ void wt_permute(const float* __restrict__ w, ushort_t* __restrict__ wt) {
    int i = blockIdx.x * 256 + threadIdx.x;
    const int total = G_ * O_ * KD;
    if (i >= total) return;
    int base = i / KD;
    int kd = i - base * KD;
    int kk = kd / F_;
    int f  = kd - kk * F_;
    wt[i] = (ushort_t)f2bf(w[base * KD + f * 3 + kk]);
}

// 512 thr = 8 waves, M-tile 256, full O=96. Wl (group weights) shared via one
// barrier; x staged per-WAVE (private LDS slab, no barrier): each x row read
// ONCE and reused by all 3 taps. 5 dense loads (8x128B segments) per f-block,
// depth-1 f-block prefetch in distinct registers.
__global__ __launch_bounds__(512, 4) void conv_mfma(
    const float* __restrict__ x, const ushort_t* __restrict__ wt,
    const float* __restrict__ bias, float* __restrict__ out)
{
    __shared__ __align__(16) ushort_t Wl[O_ * LDB];   // 56,832 B
    __shared__ __align__(16) ushort_t Xs[8 * SLAB];   // 23,040 B

    const int g    = blockIdx.y;
    const int m0   = blockIdx.x * 256;
    const int tid  = threadIdx.x;
    const int wave = tid >> 6;
    const int lane = tid & 63;
    const int ln   = lane & 15;
    const int q    = lane >> 4;

    // Stage group weights: 96 rows x 288 bf16 (stride 296)
    {
        const ushort_t* src = wt + (size_t)g * (O_ * KD);
        for (int idx = tid; idx < O_ * 36; idx += 512) {
            int o = idx / 36;
            int s = idx - o * 36;
            *(short8*)&Wl[o * LDB + s * 8] = *(const short8*)&src[o * KD + s * 8];
        }
    }
    __syncthreads();   // the only barrier

    const int m0r = m0 + wave * 32;       // this wave's 32 rows
    const int b   = m0r >> 9;
    const int tb  = m0r & 511;

    // Per-task constants for slab staging: 5 insts x 64 lanes; task -> (row, seg).
    // Slab row rr holds global t = tb + rr - 1 (rows 0..33 used).
    const float* tp[5];
    int  laddr[5];
    bool wr[5], vld[5];
    #pragma unroll
    for (int i = 0; i < 5; ++i) {
        int task = i * 64 + lane;
        int row = task >> 3;            // 0..39
        int seg = task & 7;             // 8 segs x 4 floats = 32-f block
        int tl = tb + row - 1;
        wr[i]  = row < 34;
        vld[i] = wr[i] && ((unsigned)tl < (unsigned)T_);
        int tc = tl < 0 ? 0 : (tl > T_ - 1 ? T_ - 1 : tl);
        tp[i] = x + ((size_t)((b * T_ + tc) * G_ + g) * F_ + seg * 4);
        laddr[i] = wave * SLAB + row * SROW + seg * 4;   // ushort index, 8B-aligned
    }

    auto issueX = [&](int fb, floatx4* v) {
        #pragma unroll
        for (int i = 0; i < 5; ++i)
            v[i] = *(const floatx4*)(tp[i] + fb * 32);
    };
    auto writeX = [&](const floatx4* v) {
        #pragma unroll
        for (int i = 0; i < 5; ++i) {
            if (wr[i]) {
                unsigned lo = pk2(v[i][0], v[i][1]);
                unsigned hi = pk2(v[i][2], v[i][3]);
                if (!vld[i]) { lo = 0u; hi = 0u; }
                uint2 d; d.x = lo; d.y = hi;
                *(uint2*)&Xs[laddr[i]] = d;
            }
        }
    };

    floatx4 acc[2][6];
    #pragma unroll
    for (int s = 0; s < 2; ++s)
        #pragma unroll
        for (int nt = 0; nt < 6; ++nt)
            acc[s][nt] = (floatx4){0.f, 0.f, 0.f, 0.f};

    floatx4 cur[5], nxt[5];
    issueX(0, cur);

    #pragma unroll
    for (int fb = 0; fb < 3; ++fb) {
        if (fb < 2) issueX(fb + 1, nxt);   // keep 5 loads in flight during consume
        writeX(cur);                        // waits only on cur's loads

        #pragma unroll
        for (int kk = 0; kk < 3; ++kk) {
            const short8 a0 = *(const short8*)&Xs[wave * SLAB + (ln + kk) * SROW + q * 8];
            const short8 a1 = *(const short8*)&Xs[wave * SLAB + (16 + ln + kk) * SROW + q * 8];
            const int c32 = (kk * 3 + fb) * 32;   // Wl column block kd = kk*96 + fb*32
            #pragma unroll
            for (int nt = 0; nt < 6; ++nt) {
                const short8 bb = *(const short8*)&Wl[(nt * 16 + ln) * LDB + c32 + q * 8];
                acc[0][nt] = __builtin_amdgcn_mfma_f32_16x16x32_bf16(a0, bb, acc[0][nt], 0, 0, 0);
                acc[1][nt] = __builtin_amdgcn_mfma_f32_16x16x32_bf16(a1, bb, acc[1][nt], 0, 0, 0);
            }
        }
        #pragma unroll
        for (int i = 0; i < 5; ++i) cur[i] = nxt[i];
    }

    // Epilogue: D row = q*4 + reg, col = ln; + bias; f32 out.
    #pragma unroll
    for (int s = 0; s < 2; ++s) {
        int mbase = m0 + wave * 32 + s * 16 + q * 4;
        #pragma unroll
        for (int nt = 0; nt < 6; ++nt) {
            int o = nt * 16 + ln;
            float bv = bias[g * O_ + o];
            #pragma unroll
            for (int r = 0; r < 4; ++r) {
                int m = mbase + r;
                out[(size_t)(m * G_ + g) * O_ + o] = acc[s][nt][r] + bv;
            }
        }
    }
}

extern "C" void kernel_launch(void* const* d_in, const int* in_sizes, int n_in,
                              void* d_out, int out_size, void* d_ws, size_t ws_size,
                              hipStream_t stream) {
    const float* x    = (const float*)d_in[0];
    const float* w    = (const float*)d_in[1];
    const float* bias = (const float*)d_in[2];
    float* out = (float*)d_out;
    ushort_t* wt = (ushort_t*)d_ws;   // 129*96*288*2 = 7,133,184 B

    const int total_w = G_ * O_ * KD;
    wt_permute<<<dim3((total_w + 255) / 256), dim3(256), 0, stream>>>(w, wt);

    dim3 grid(2048 / 256, G_);
    conv_mfma<<<grid, dim3(512), 0, stream>>>(x, wt, bias, out);
}